// Round 1
// baseline (975.973 us; speedup 1.0000x reference)
//
#include <hip/hip_runtime.h>

#define BATCH 256
#define SEQ   780
#define DIM   1024
#define TOK   195   // MAX_TOKENS

__global__ __launch_bounds__(256) void AvgPoolingMerger_90563680403997_kernel(
    const float* __restrict__ hs,        // [B, S, D]
    const int*   __restrict__ grid_thw,  // [B, 3]
    float* __restrict__ out,             // [B, TOK, D]
    float* __restrict__ attn)            // [B, TOK] (written as float 0/1)
{
    const int j = blockIdx.x;   // pooled token index [0, TOK)
    const int b = blockIdx.y;   // batch index
    const int t = threadIdx.x;  // 256 threads -> one float4 each (D=1024)

    const int h  = grid_thw[b * 3 + 1];
    const int w  = grid_thw[b * 3 + 2];
    const int W2 = w >> 1;              // pre-pool grid width
    const int Hp = h >> 2;              // pooled grid height
    const int Wp = w >> 2;              // pooled grid width
    const int n_out = Hp * Wp;

    float4* outp = (float4*)(out + ((size_t)b * TOK + j) * DIM);

    if (j >= n_out) {
        outp[t] = make_float4(0.f, 0.f, 0.f, 0.f);
        if (t == 0) attn[(size_t)b * TOK + j] = 0.0f;
        return;
    }

    const int r = j / Wp;
    const int c = j - r * Wp;
    const int row_base = (2 * r) * W2 + 2 * c;   // top-left token of 2x2 window

    // rows row_base and row_base+1 are contiguous: one 8KB span; same for +W2.
    const float4* span0 = (const float4*)(hs + ((size_t)b * SEQ + row_base) * DIM);
    const float4* span1 = (const float4*)(hs + ((size_t)b * SEQ + row_base + W2) * DIM);

    const float4 a0 = span0[t];
    const float4 a1 = span0[t + DIM / 4];
    const float4 a2 = span1[t];
    const float4 a3 = span1[t + DIM / 4];

    float4 res;
    res.x = (a0.x + a1.x + a2.x + a3.x) * 0.25f;
    res.y = (a0.y + a1.y + a2.y + a3.y) * 0.25f;
    res.z = (a0.z + a1.z + a2.z + a3.z) * 0.25f;
    res.w = (a0.w + a1.w + a2.w + a3.w) * 0.25f;
    outp[t] = res;

    if (t == 0) attn[(size_t)b * TOK + j] = 1.0f;
}

extern "C" void kernel_launch(void* const* d_in, const int* in_sizes, int n_in,
                              void* d_out, int out_size, void* d_ws, size_t ws_size,
                              hipStream_t stream) {
    const float* hs       = (const float*)d_in[0];  // hidden_states [B,S,D] fp32
    // d_in[1] = attention_mask [B,S] int32 (unused by the computation)
    const int*   grid_thw = (const int*)d_in[2];    // image_grid_thw [B,3] int32

    float* out  = (float*)d_out;                    // [B, TOK, D]
    float* attn = out + (size_t)BATCH * TOK * DIM;  // [B, TOK] as float 0/1

    dim3 grid(TOK, BATCH);
    AvgPoolingMerger_90563680403997_kernel<<<grid, 256, 0, stream>>>(hs, grid_thw, out, attn);
}

// Round 3
// 957.389 us; speedup vs baseline: 1.0194x; 1.0194x over previous
//
#include <hip/hip_runtime.h>

#define BATCH 256
#define SEQ   780
#define DIM   1024
#define TOK   195   // MAX_TOKENS

// native clang vector type — required by __builtin_nontemporal_load/store
typedef float v4f __attribute__((ext_vector_type(4)));

__global__ __launch_bounds__(256) void AvgPoolingMerger_90563680403997_kernel(
    const float* __restrict__ hs,        // [B, S, D]
    const int*   __restrict__ grid_thw,  // [B, 3]
    float* __restrict__ out,             // [B, TOK, D]
    float* __restrict__ attn)            // [B, TOK] (written as float 0/1)
{
    const int j = blockIdx.x;   // pooled token index [0, TOK)
    const int b = blockIdx.y;   // batch index
    const int t = threadIdx.x;  // 256 threads -> one v4f each (D=1024)

    const int h  = grid_thw[b * 3 + 1];
    const int w  = grid_thw[b * 3 + 2];
    const int W2 = w >> 1;              // pre-pool grid width
    const int Wp = w >> 2;              // pooled grid width
    const int n_out = (h >> 2) * Wp;

    v4f* outp = (v4f*)(out + ((size_t)b * TOK + j) * DIM);

    if (j >= n_out) {
        // zero-fill: write-once stream, bypass cache allocate
        v4f z = {0.f, 0.f, 0.f, 0.f};
        __builtin_nontemporal_store(z, outp + t);
        if (t == 0) attn[(size_t)b * TOK + j] = 0.0f;
        return;
    }

    const int r = j / Wp;
    const int c = j - r * Wp;
    const int row_base = (2 * r) * W2 + 2 * c;   // top-left token of 2x2 window

    // rows row_base and row_base+1 are contiguous: one 8KB span; same for +W2.
    const v4f* span0 = (const v4f*)(hs + ((size_t)b * SEQ + row_base) * DIM);
    const v4f* span1 = (const v4f*)(hs + ((size_t)b * SEQ + row_base + W2) * DIM);

    // read-once stream: non-temporal loads keep 818MB hidden_states out of L2/L3
    const v4f a0 = __builtin_nontemporal_load(span0 + t);
    const v4f a1 = __builtin_nontemporal_load(span0 + t + DIM / 4);
    const v4f a2 = __builtin_nontemporal_load(span1 + t);
    const v4f a3 = __builtin_nontemporal_load(span1 + t + DIM / 4);

    v4f res = (a0 + a1 + a2 + a3) * 0.25f;
    __builtin_nontemporal_store(res, outp + t);

    if (t == 0) attn[(size_t)b * TOK + j] = 1.0f;
}

extern "C" void kernel_launch(void* const* d_in, const int* in_sizes, int n_in,
                              void* d_out, int out_size, void* d_ws, size_t ws_size,
                              hipStream_t stream) {
    const float* hs       = (const float*)d_in[0];  // hidden_states [B,S,D] fp32
    // d_in[1] = attention_mask [B,S] int32 (unused by the computation)
    const int*   grid_thw = (const int*)d_in[2];    // image_grid_thw [B,3] int32

    float* out  = (float*)d_out;                    // [B, TOK, D]
    float* attn = out + (size_t)BATCH * TOK * DIM;  // [B, TOK] as float 0/1

    dim3 grid(TOK, BATCH);
    AvgPoolingMerger_90563680403997_kernel<<<grid, 256, 0, stream>>>(hs, grid_thw, out, attn);
}